// Round 6
// baseline (230.444 us; speedup 1.0000x reference)
//
#include <hip/hip_runtime.h>
#include <hip/hip_bf16.h>

#define NQ 2048
#define NB 2

typedef unsigned short u16;
typedef unsigned int u32;
typedef _Float16 f16;
typedef __attribute__((ext_vector_type(8))) _Float16 half8;
typedef __attribute__((ext_vector_type(2))) __fp16 fp16x2;
typedef __attribute__((ext_vector_type(4))) float f32x4;
typedef __attribute__((ext_vector_type(2))) unsigned int u32x2;

#define MFMAH(A, B, C) __builtin_amdgcn_mfma_f32_16x16x32_f16(A, B, C, 0, 0, 0)

__device__ __forceinline__ u16 f2h(float x) {
    f16 h = (f16)x;                 // v_cvt_f16_f32 (RNE)
    return *(u16*)&h;
}
// packed f32x2 -> fp16x2 (v_cvt_pkrtz_f16_f32), returned as u32
__device__ __forceinline__ u32 pk_h2(float a, float b) {
    union { fp16x2 v; u32 u; } c;
    c.v = __builtin_amdgcn_cvt_pkrtz(a, b);
    return c.u;
}
// raw v_exp_f32 (2^x)
__device__ __forceinline__ float fexp2(float x) {
#if __has_builtin(__builtin_amdgcn_exp2f)
    return __builtin_amdgcn_exp2f(x);
#else
    return exp2f(x);
#endif
}
// async global->LDS DMA, 16B/lane; lds dest is wave-uniform base + lane*16
__device__ __forceinline__ void glds16(const u16* g, u16* l) {
    typedef const __attribute__((address_space(1))) u16 gu16;
    typedef __attribute__((address_space(3))) u16 lu16;
    __builtin_amdgcn_global_load_lds((gu16*)g, (lu16*)l, 16, 0, 0);
}
// VALU cross-lane swaps (gfx950): a/b both updated.
// pl32: a' = [a.lo32, b.lo32], b' = [a.hi32, b.hi32]
__device__ __forceinline__ void pl32swap(u32& a, u32& b) {
#if __has_builtin(__builtin_amdgcn_permlane32_swap)
    u32x2 r = __builtin_amdgcn_permlane32_swap(a, b, false, false);
    a = r[0]; b = r[1];
#else
    asm volatile("v_permlane32_swap_b32 %0, %1" : "+v"(a), "+v"(b));
#endif
}
// pl16: a' = [a.q0, b.q0, a.q2, b.q2], b' = [a.q1, b.q1, a.q3, b.q3]  (q = 16-lane row)
__device__ __forceinline__ void pl16swap(u32& a, u32& b) {
#if __has_builtin(__builtin_amdgcn_permlane16_swap)
    u32x2 r = __builtin_amdgcn_permlane16_swap(a, b, false, false);
    a = r[0]; b = r[1];
#else
    asm volatile("v_permlane16_swap_b32 %0, %1" : "+v"(a), "+v"(b));
#endif
}

// q-scale: 1/sqrt(64) * log2(e), so attention scores land in log2 domain
#define QSCALE 0.18033688011112042f

// ============ merge to fp16: rows 0..3071 = q,k,v; 3072..4095 = o ============
// vectorized x4: one block = one 1024-col row, float4 loads, ushort4 store
__global__ __launch_bounds__(256) void merge_w16(
    const float* __restrict__ w0, const float* __restrict__ dw0, const float* __restrict__ db0,
    const float* __restrict__ w1, const float* __restrict__ dw1, const float* __restrict__ db1,
    const float* __restrict__ w2, const float* __restrict__ dw2, const float* __restrict__ db2,
    const float* __restrict__ w3, const float* __restrict__ dw3, const float* __restrict__ db3,
    u16* __restrict__ Wf) {
    int i4 = (blockIdx.x * 256 + threadIdx.x) * 4;   // over 4096*1024
    int row = i4 >> 10, col = i4 & 1023;
    int which = row >> 10, lr = row & 1023;
    const float* W  = (which == 0) ? w0  : (which == 1) ? w1  : (which == 2) ? w2  : w3;
    const float* dW = (which == 0) ? dw0 : (which == 1) ? dw1 : (which == 2) ? dw2 : dw3;
    const float* dB = (which == 0) ? db0 : (which == 1) ? db1 : (which == 2) ? db2 : db3;
    float4 acc = *(const float4*)&W[lr * 1024 + col];
#pragma unroll
    for (int r = 0; r < 5; ++r) {
        float s = dB[lr * 5 + r];                    // block-uniform
        float4 w4 = *(const float4*)&dW[r * 1024 + col];
        acc.x += s * w4.x; acc.y += s * w4.y;
        acc.z += s * w4.z; acc.w += s * w4.w;
    }
    if (which == 0) { acc.x *= QSCALE; acc.y *= QSCALE; acc.z *= QSCALE; acc.w *= QSCALE; }
    ushort4 o = make_ushort4(f2h(acc.x), f2h(acc.y), f2h(acc.z), f2h(acc.w));
    *(ushort4*)&Wf[i4] = o;
}

__global__ __launch_bounds__(256) void bias_pack(
    const float* __restrict__ b0, const float* __restrict__ b1,
    const float* __restrict__ b2, const float* __restrict__ b3,
    float* __restrict__ ball) {
    int t = blockIdx.x * 256 + threadIdx.x;   // 4096
    int which = t >> 10;
    const float* B = (which == 0) ? b0 : (which == 1) ? b1 : (which == 2) ? b2 : b3;
    float v = B[t & 1023];
    if (which == 0) v *= QSCALE;
    ball[t] = v;
}

// x -> single fp16 (RNE)
__global__ __launch_bounds__(256) void xcast(const float* __restrict__ x,
                                             u16* __restrict__ xf) {
    int i4 = (blockIdx.x * 256 + threadIdx.x) * 4;
    float4 v = *(const float4*)&x[i4];
    *(uint2*)&xf[i4] = make_uint2(pk_h2(v.x, v.y), pk_h2(v.z, v.w));
}

// ============ fp16 GEMM: C[4096][N] = A @ B^T + bias ============
// Single fp16 product. TM x 128 tile, BK=64 staged as two 32-col halves
// (each half keeps the packed [row][32] m97 bank layout), global_load_lds(16).
// If VtOut: column blocks bn >= 2048 (V third of fused QKV) store TRANSPOSED
// to VtOut[(col-2048)][4096].
template <int TM>
__global__ __launch_bounds__(256) void gemm_f16(
    const u16* __restrict__ Af, const u16* __restrict__ Bf,
    const float* __restrict__ bias,
    float* __restrict__ Cf, u16* __restrict__ Cb, int ldc,
    u16* __restrict__ VtOut) {
    constexpr int MI = TM / 32;               // m-subtiles per wave
    __shared__ u16 As[2][TM * 32];
    __shared__ u16 Bs[2][128 * 32];
    const int tid = threadIdx.x;
    const int wid = tid >> 6, lane = tid & 63;
    const int ln = lane & 15, quad = lane >> 4;
    const int bm = blockIdx.y * TM, bn = blockIdx.x * 128;
    const int wm = (wid >> 1) * (TM / 2), wn = (wid & 1) * 64;
    const int lrow = lane >> 2;               // DMA: row within 16-row group
    const int lchunk = (lane & 3) * 8;        // DMA: u16 offset of 16B chunk

    f32x4 acc[MI][4];
#pragma unroll
    for (int i = 0; i < MI; ++i)
#pragma unroll
        for (int j = 0; j < 4; ++j) acc[i][j] = (f32x4){0.f, 0.f, 0.f, 0.f};

    for (int k0 = 0; k0 < 1024; k0 += 64) {
#pragma unroll
        for (int hf = 0; hf < 2; ++hf) {
#pragma unroll
            for (int p = 0; p < TM / 64; ++p) {
                int r = p * 64 + wid * 16;
                glds16(&Af[(bm + r + lrow) * 1024 + k0 + hf * 32 + lchunk],
                       &As[hf][r * 32]);
            }
#pragma unroll
            for (int p = 0; p < 2; ++p) {
                int r = p * 64 + wid * 16;
                glds16(&Bf[(bn + r + lrow) * 1024 + k0 + hf * 32 + lchunk],
                       &Bs[hf][r * 32]);
            }
        }
        asm volatile("s_waitcnt vmcnt(0)" ::: "memory");
        __syncthreads();

        half8 a[MI][2], b[4][2];
#pragma unroll
        for (int kc = 0; kc < 2; ++kc) {
#pragma unroll
            for (int j = 0; j < 4; ++j)
                b[j][kc] = *(const half8*)&Bs[kc][(wn + j * 16 + ln) * 32 + quad * 8];
#pragma unroll
            for (int i = 0; i < MI; ++i)
                a[i][kc] = *(const half8*)&As[kc][(wm + i * 16 + ln) * 32 + quad * 8];
        }
#pragma unroll
        for (int i = 0; i < MI; ++i)
#pragma unroll
            for (int j = 0; j < 4; ++j) {
                acc[i][j] = MFMAH(a[i][0], b[j][0], acc[i][j]);
                acc[i][j] = MFMAH(a[i][1], b[j][1], acc[i][j]);
            }
        __syncthreads();
    }

    if (VtOut && bn >= 2048) {
        // transposed store: VtOut[d][seq]; lane holds 4 consecutive seq rows.
#pragma unroll
        for (int i = 0; i < MI; ++i)
#pragma unroll
            for (int j = 0; j < 4; ++j) {
                int col = bn + wn + j * 16 + ln;
                float bv = bias[col];
                int colV = col - 2048;
                int row0 = bm + wm + i * 16 + quad * 4;
                ushort4 pk = make_ushort4(f2h(acc[i][j][0] + bv), f2h(acc[i][j][1] + bv),
                                          f2h(acc[i][j][2] + bv), f2h(acc[i][j][3] + bv));
                *(ushort4*)&VtOut[colV * 4096 + row0] = pk;
            }
        return;
    }

#pragma unroll
    for (int i = 0; i < MI; ++i)
#pragma unroll
        for (int j = 0; j < 4; ++j) {
            int col = bn + wn + j * 16 + ln;
            float bv = bias[col];
#pragma unroll
            for (int r = 0; r < 4; ++r) {
                int row = bm + wm + i * 16 + quad * 4 + r;
                float v = acc[i][j][r] + bv;
                if (Cb) Cb[row * ldc + col] = f2h(v);
                else    Cf[row * ldc + col] = v;
            }
        }
}

// ============ flash attention, fp16 MFMA, transposed S/O ============
// Block: 2 waves x 32 q-rows = 64 q of one (b,h); grid 1024 -> 4 blocks/CU
// (R5 lesson: with 4-wave blocks only 2 barrier-locked blocks/CU ran; all
// pipes <40%. Smaller independent blocks = 4 independent barrier domains/CU,
// so one block's vmcnt/barrier drain overlaps another's compute.)
// K AND V staged via glds16 into packed [row][32]-per-half layout with XOR
// chunk swizzle, both-sides -> 0 bank conflicts (verified R4). Cross-tile
// pipeline: stage(kt+2) || QK(kt+1)+exp || PV(kt); even/odd phases, named
// pfA/pfB, peeled tail, branch-free body. Scores in log2 domain ->
// p = v_exp_f32 raw. Row sums via ones-MFMA.
__global__ __launch_bounds__(128) void flash_f16(
    const u16* __restrict__ QKV, const u16* __restrict__ Vt,
    u16* __restrict__ AO) {
    __shared__ u16 Ks[2][2][64 * 32];   // [buf][d-half][key row][32], chunk-swizzled
    __shared__ u16 Vs[2][2][64 * 32];   // [buf][key-half][d row][32], chunk-swizzled

    const int tid = threadIdx.x;
    const int wid = tid >> 6, lane = tid & 63;
    const int ln = lane & 15, quad = lane >> 4;
    const int qt = blockIdx.x, h = blockIdx.y, b = blockIdx.z;
    const int rowbase = b * NQ;
    const int col0 = h * 64;
    const int q0 = rowbase + qt * 64 + wid * 32;
    const int lrow = lane >> 2;          // DMA: row within 16-row group
    // DMA source chunk (pre-swizzle): lane l fetches logical chunk (l&3)^((lrow>>1)&3)
    const int kchunk = ((lane & 3) ^ ((lrow >> 1) & 3)) * 8;
    // fragment-read physical chunk: quad ^ ((row>>1)&3), (row>>1)&3 == (ln>>1)&3
    const int kswz = (quad ^ ((ln >> 1) & 3)) * 8;

    const half8 ones = {(f16)1, (f16)1, (f16)1, (f16)1,
                        (f16)1, (f16)1, (f16)1, (f16)1};

    // Q fragments (B-operand: lane ln = q-row q0+mi*16+ln, k = kc*32+quad*8+j)
    half8 qf[2][2];
#pragma unroll
    for (int mi = 0; mi < 2; ++mi)
#pragma unroll
        for (int kc = 0; kc < 2; ++kc)
            qf[mi][kc] = *(const half8*)&QKV[(q0 + mi * 16 + ln) * 3072 + col0 +
                                             kc * 32 + quad * 8];

    f32x4 accO[4][2];    // [a: d-subtile][mi], element (d=a*16+quad*4+r, q=mi*16+ln)
    f32x4 accS[2];       // row sums, col = q = ln
#pragma unroll
    for (int mi = 0; mi < 2; ++mi) {
        accS[mi] = (f32x4){0.f, 0.f, 0.f, 0.f};
#pragma unroll
        for (int a = 0; a < 4; ++a) accO[a][mi] = (f32x4){0.f, 0.f, 0.f, 0.f};
    }

    const int NT = NQ / 64;
    // DMA per-lane global bases; each wave stages 32 rows (2 glds16 per half)
    const u16* Kg = QKV + (rowbase + wid * 32 + lrow) * 3072 + 1024 + col0 + kchunk;
    const u16* Vg = Vt + (col0 + wid * 32 + lrow) * 4096 + rowbase + kchunk;

#define STAGEK(kt2, bu)                                              \
    {                                                                \
        const u16* kg_ = Kg + (kt2) * (64 * 3072);                   \
        glds16(kg_,             &Ks[bu][0][wid * 1024]);             \
        glds16(kg_ + 32,        &Ks[bu][1][wid * 1024]);             \
        glds16(kg_ + 16 * 3072,      &Ks[bu][0][wid * 1024 + 512]);  \
        glds16(kg_ + 16 * 3072 + 32, &Ks[bu][1][wid * 1024 + 512]);  \
    }
#define STAGEV(kt2, bu)                                              \
    {                                                                \
        const u16* vg_ = Vg + (kt2) * 64;                            \
        glds16(vg_,             &Vs[bu][0][wid * 1024]);             \
        glds16(vg_ + 32,        &Vs[bu][1][wid * 1024]);             \
        glds16(vg_ + 16 * 4096,      &Vs[bu][0][wid * 1024 + 512]);  \
        glds16(vg_ + 16 * 4096 + 32, &Vs[bu][1][wid * 1024 + 512]);  \
    }

    // QK^T from Ks[kb] -> exp -> butterfly -> pf (B-operand layout) + rowsum.
    auto qk_exp = [&](int kb, half8 (&pf)[2][2]) {
        // S^T = K @ Q^T : element (key = a*16+quad*4+r, q = mi*16+ln)
        f32x4 s[4][2];
#pragma unroll
        for (int a = 0; a < 4; ++a) {
            half8 kf0 = *(const half8*)&Ks[kb][0][(a * 16 + ln) * 32 + kswz];
            half8 kf1 = *(const half8*)&Ks[kb][1][(a * 16 + ln) * 32 + kswz];
#pragma unroll
            for (int mi = 0; mi < 2; ++mi) {
                f32x4 t = (f32x4){0.f, 0.f, 0.f, 0.f};
                t = MFMAH(kf0, qf[mi][0], t);
                t = MFMAH(kf1, qf[mi][1], t);
                s[a][mi] = t;
            }
        }
        // p = 2^s, pack to fp16 pairs, register butterfly to B-operand layout:
        // pf[mi][kc] element j = P[key = kc*32 + quad*8 + j][q = mi*16+ln].
#pragma unroll
        for (int mi = 0; mi < 2; ++mi)
#pragma unroll
            for (int kc = 0; kc < 2; ++kc) {
                u32 c0 = pk_h2(fexp2(s[2 * kc][mi][0]), fexp2(s[2 * kc][mi][1]));
                u32 c1 = pk_h2(fexp2(s[2 * kc][mi][2]), fexp2(s[2 * kc][mi][3]));
                u32 c2 = pk_h2(fexp2(s[2 * kc + 1][mi][0]), fexp2(s[2 * kc + 1][mi][1]));
                u32 c3 = pk_h2(fexp2(s[2 * kc + 1][mi][2]), fexp2(s[2 * kc + 1][mi][3]));
                pl32swap(c0, c2);
                pl32swap(c1, c3);
                pl16swap(c0, c2);
                pl16swap(c1, c3);
                union { u32 u[4]; half8 h; } pu;
                pu.u[0] = c0; pu.u[1] = c1; pu.u[2] = c2; pu.u[3] = c3;
                pf[mi][kc] = pu.h;
                accS[mi] = MFMAH(ones, pf[mi][kc], accS[mi]);   // row sums
            }
    };

    // O^T += V^T @ P^T from Vs[vb] : element (d = a*16+quad*4+r, q = mi*16+ln)
    auto pv = [&](const half8 (&pf)[2][2], int vb) {
#pragma unroll
        for (int a = 0; a < 4; ++a) {
            half8 vf0 = *(const half8*)&Vs[vb][0][(a * 16 + ln) * 32 + kswz];
            half8 vf1 = *(const half8*)&Vs[vb][1][(a * 16 + ln) * 32 + kswz];
#pragma unroll
            for (int mi = 0; mi < 2; ++mi) {
                accO[a][mi] = MFMAH(vf0, pf[mi][0], accO[a][mi]);
                accO[a][mi] = MFMAH(vf1, pf[mi][1], accO[a][mi]);
            }
        }
    };

    half8 pfA[2][2], pfB[2][2];

    // prologue: tile 0 staged, pfA = P(0); K(1) staged for first phase
    STAGEK(0, 0);
    STAGEV(0, 0);
    asm volatile("s_waitcnt vmcnt(0)" ::: "memory");
    __syncthreads();
    STAGEK(1, 1);
    qk_exp(0, pfA);
    asm volatile("s_waitcnt vmcnt(0)" ::: "memory");
    __syncthreads();

    // main loop: branch-free even/odd phases, 2 tiles/iteration.
    // phase A: writes Ks[0],Vs[1]; reads Ks[1](QK kt+1), Vs[0](PV kt).
    // phase B: writes Ks[1],Vs[0]; reads Ks[0](QK kt+2), Vs[1](PV kt+1).
    for (int kt = 0; kt < NT - 2; kt += 2) {
        STAGEK(kt + 2, 0);
        STAGEV(kt + 1, 1);
        qk_exp(1, pfB);          // tile kt+1 (exp overlaps PV below)
        pv(pfA, 0);              // tile kt
        asm volatile("s_waitcnt vmcnt(0)" ::: "memory");
        __syncthreads();

        STAGEK(kt + 3, 1);
        STAGEV(kt + 2, 0);
        qk_exp(0, pfA);          // tile kt+2
        pv(pfB, 1);              // tile kt+1
        asm volatile("s_waitcnt vmcnt(0)" ::: "memory");
        __syncthreads();
    }
    // tail: tiles NT-2, NT-1 (state: pfA = P(NT-2), Ks[1]=K(NT-1), Vs[0]=V(NT-2))
    STAGEV(NT - 1, 1);
    qk_exp(1, pfB);              // tile NT-1
    pv(pfA, 0);                  // tile NT-2
    asm volatile("s_waitcnt vmcnt(0)" ::: "memory");
    __syncthreads();
    pv(pfB, 1);                  // tile NT-1
#undef STAGEK
#undef STAGEV

    // epilogue: normalize (inv uniform per lane), single fp16 AO, ushort4 stores
#pragma unroll
    for (int mi = 0; mi < 2; ++mi) {
        float inv = 1.f / accS[mi][0];
        int q = q0 + mi * 16 + ln;
#pragma unroll
        for (int a = 0; a < 4; ++a) {
            ushort4 pk = make_ushort4(f2h(accO[a][mi][0] * inv),
                                      f2h(accO[a][mi][1] * inv),
                                      f2h(accO[a][mi][2] * inv),
                                      f2h(accO[a][mi][3] * inv));
            *(ushort4*)&AO[q * 1024 + col0 + a * 16 + quad * 4] = pk;
        }
    }
}

// ============ launch ============
extern "C" void kernel_launch(void* const* d_in, const int* in_sizes, int n_in,
                              void* d_out, int out_size, void* d_ws, size_t ws_size,
                              hipStream_t stream) {
    const float* x = (const float*)d_in[0];
    const float* w[4]  = {(const float*)d_in[1],  (const float*)d_in[5],
                          (const float*)d_in[9],  (const float*)d_in[13]};
    const float* bv[4] = {(const float*)d_in[2],  (const float*)d_in[6],
                          (const float*)d_in[10], (const float*)d_in[14]};
    const float* dw[4] = {(const float*)d_in[3],  (const float*)d_in[7],
                          (const float*)d_in[11], (const float*)d_in[15]};
    const float* db[4] = {(const float*)d_in[4],  (const float*)d_in[8],
                          (const float*)d_in[12], (const float*)d_in[16]};

    u16* p = (u16*)d_ws;
    u16* Wf  = p; p += 4096 * 1024;
    u16* xf  = p; p += 4096 * 1024;
    u16* QKV = p; p += 4096 * 3072;   // V third unused (lives in Vt)
    u16* Vt  = p; p += 1024 * 4096;
    float* ball = (float*)p;          // 4096 floats
    // AO aliases xf: x is dead after the QKV GEMM completes (same stream).
    u16* AO = xf;

    merge_w16<<<4096, 256, 0, stream>>>(w[0], dw[0], db[0], w[1], dw[1], db[1],
                                        w[2], dw[2], db[2], w[3], dw[3], db[3], Wf);
    bias_pack<<<16, 256, 0, stream>>>(bv[0], bv[1], bv[2], bv[3], ball);
    xcast<<<4096, 256, 0, stream>>>(x, xf);

    // fused q,k,v projection: q,k -> QKV fp16 row-major; v -> Vt transposed
    gemm_f16<128><<<dim3(24, 32), 256, 0, stream>>>(xf, Wf, ball,
                                                    nullptr, QKV, 3072, Vt);

    flash_f16<<<dim3(NQ / 64, 16, NB), 128, 0, stream>>>(QKV, Vt, AO);

    // o projection: fp32 out, TM=64 -> 512 blocks (2 blocks/CU)
    gemm_f16<64><<<dim3(8, 64), 256, 0, stream>>>(AO, Wf + 3072 * 1024,
                                                  ball + 3072, (float*)d_out, nullptr, 1024,
                                                  nullptr);
}

// Round 7
// 225.193 us; speedup vs baseline: 1.0233x; 1.0233x over previous
//
#include <hip/hip_runtime.h>
#include <hip/hip_bf16.h>

#define NQ 2048
#define NB 2

typedef unsigned short u16;
typedef unsigned int u32;
typedef _Float16 f16;
typedef __attribute__((ext_vector_type(8))) _Float16 half8;
typedef __attribute__((ext_vector_type(2))) __fp16 fp16x2;
typedef __attribute__((ext_vector_type(4))) float f32x4;
typedef __attribute__((ext_vector_type(2))) unsigned int u32x2;

#define MFMAH(A, B, C) __builtin_amdgcn_mfma_f32_16x16x32_f16(A, B, C, 0, 0, 0)

__device__ __forceinline__ u16 f2h(float x) {
    f16 h = (f16)x;                 // v_cvt_f16_f32 (RNE)
    return *(u16*)&h;
}
// packed f32x2 -> fp16x2 (v_cvt_pkrtz_f16_f32), returned as u32
__device__ __forceinline__ u32 pk_h2(float a, float b) {
    union { fp16x2 v; u32 u; } c;
    c.v = __builtin_amdgcn_cvt_pkrtz(a, b);
    return c.u;
}
// raw v_exp_f32 (2^x)
__device__ __forceinline__ float fexp2(float x) {
#if __has_builtin(__builtin_amdgcn_exp2f)
    return __builtin_amdgcn_exp2f(x);
#else
    return exp2f(x);
#endif
}
// async global->LDS DMA, 16B/lane; lds dest is wave-uniform base + lane*16
__device__ __forceinline__ void glds16(const u16* g, u16* l) {
    typedef const __attribute__((address_space(1))) u16 gu16;
    typedef __attribute__((address_space(3))) u16 lu16;
    __builtin_amdgcn_global_load_lds((gu16*)g, (lu16*)l, 16, 0, 0);
}
// VALU cross-lane swaps (gfx950): a/b both updated.
__device__ __forceinline__ void pl32swap(u32& a, u32& b) {
#if __has_builtin(__builtin_amdgcn_permlane32_swap)
    u32x2 r = __builtin_amdgcn_permlane32_swap(a, b, false, false);
    a = r[0]; b = r[1];
#else
    asm volatile("v_permlane32_swap_b32 %0, %1" : "+v"(a), "+v"(b));
#endif
}
__device__ __forceinline__ void pl16swap(u32& a, u32& b) {
#if __has_builtin(__builtin_amdgcn_permlane16_swap)
    u32x2 r = __builtin_amdgcn_permlane16_swap(a, b, false, false);
    a = r[0]; b = r[1];
#else
    asm volatile("v_permlane16_swap_b32 %0, %1" : "+v"(a), "+v"(b));
#endif
}

// q-scale: 1/sqrt(64) * log2(e), so attention scores land in log2 domain
#define QSCALE 0.18033688011112042f

// ============ merge to fp16 (+ fused bias pack) ============
// blocks 0..4095: W + dB@dW -> fp16 rows (q,k,v,o); blocks 4096..4111: bias
__global__ __launch_bounds__(256) void merge_w16(
    const float* __restrict__ w0, const float* __restrict__ dw0, const float* __restrict__ db0,
    const float* __restrict__ w1, const float* __restrict__ dw1, const float* __restrict__ db1,
    const float* __restrict__ w2, const float* __restrict__ dw2, const float* __restrict__ db2,
    const float* __restrict__ w3, const float* __restrict__ dw3, const float* __restrict__ db3,
    u16* __restrict__ Wf,
    const float* __restrict__ b0, const float* __restrict__ b1,
    const float* __restrict__ b2, const float* __restrict__ b3,
    float* __restrict__ ball) {
    if (blockIdx.x >= 4096) {
        int t = (blockIdx.x - 4096) * 256 + threadIdx.x;   // 4096
        int which = t >> 10;
        const float* B = (which == 0) ? b0 : (which == 1) ? b1 : (which == 2) ? b2 : b3;
        float v = B[t & 1023];
        if (which == 0) v *= QSCALE;
        ball[t] = v;
        return;
    }
    int i4 = (blockIdx.x * 256 + threadIdx.x) * 4;   // over 4096*1024
    int row = i4 >> 10, col = i4 & 1023;
    int which = row >> 10, lr = row & 1023;
    const float* W  = (which == 0) ? w0  : (which == 1) ? w1  : (which == 2) ? w2  : w3;
    const float* dW = (which == 0) ? dw0 : (which == 1) ? dw1 : (which == 2) ? dw2 : dw3;
    const float* dB = (which == 0) ? db0 : (which == 1) ? db1 : (which == 2) ? db2 : db3;
    float4 acc = *(const float4*)&W[lr * 1024 + col];
#pragma unroll
    for (int r = 0; r < 5; ++r) {
        float s = dB[lr * 5 + r];                    // block-uniform
        float4 w4 = *(const float4*)&dW[r * 1024 + col];
        acc.x += s * w4.x; acc.y += s * w4.y;
        acc.z += s * w4.z; acc.w += s * w4.w;
    }
    if (which == 0) { acc.x *= QSCALE; acc.y *= QSCALE; acc.z *= QSCALE; acc.w *= QSCALE; }
    ushort4 o = make_ushort4(f2h(acc.x), f2h(acc.y), f2h(acc.z), f2h(acc.w));
    *(ushort4*)&Wf[i4] = o;
}

// x -> single fp16 (RNE)
__global__ __launch_bounds__(256) void xcast(const float* __restrict__ x,
                                             u16* __restrict__ xf) {
    int i4 = (blockIdx.x * 256 + threadIdx.x) * 4;
    float4 v = *(const float4*)&x[i4];
    *(uint2*)&xf[i4] = make_uint2(pk_h2(v.x, v.y), pk_h2(v.z, v.w));
}

// ============ fp16 GEMM: C[4096][N] = A @ B^T + bias ============
// TM x 128 tile, BK=32 K-steps, TRUE 2-phase double buffer: STAGE(k+1) is
// issued BEFORE computing step k (T3-minimum; the old schedule drained
// vmcnt(0) immediately after staging -> latency fully exposed each step).
// LDS total 32KB (TM=128) so occupancy is unchanged. Packed [row][32]
// layout with the R4-verified XOR chunk swizzle both-sides -> 0 conflicts.
// If VtOut: column blocks bn >= 2048 (V third) store TRANSPOSED.
template <int TM>
__global__ __launch_bounds__(256) void gemm_f16(
    const u16* __restrict__ Af, const u16* __restrict__ Bf,
    const float* __restrict__ bias,
    float* __restrict__ Cf, u16* __restrict__ Cb, int ldc,
    u16* __restrict__ VtOut) {
    constexpr int MI = TM / 32;               // m-subtiles per wave
    __shared__ u16 As[2][TM * 32];            // [buf][row*32]
    __shared__ u16 Bs[2][128 * 32];
    const int tid = threadIdx.x;
    const int wid = tid >> 6, lane = tid & 63;
    const int ln = lane & 15, quad = lane >> 4;
    const int bm = blockIdx.y * TM, bn = blockIdx.x * 128;
    const int wm = (wid >> 1) * (TM / 2), wn = (wid & 1) * 64;
    const int lrow = lane >> 2;               // DMA: row within 16-row group
    // DMA source chunk (pre-swizzle): lane l fetches logical chunk (l&3)^((lrow>>1)&3)
    const int schunk = ((lane & 3) ^ ((lrow >> 1) & 3)) * 8;
    // fragment-read physical chunk: quad ^ ((ln>>1)&3)
    const int kswz = (quad ^ ((ln >> 1) & 3)) * 8;

    f32x4 acc[MI][4];
#pragma unroll
    for (int i = 0; i < MI; ++i)
#pragma unroll
        for (int j = 0; j < 4; ++j) acc[i][j] = (f32x4){0.f, 0.f, 0.f, 0.f};

    auto GSTAGE = [&](int k0, int bu) {
#pragma unroll
        for (int p = 0; p < TM / 64; ++p) {
            int r = p * 64 + wid * 16;
            glds16(&Af[(bm + r + lrow) * 1024 + k0 + schunk], &As[bu][r * 32]);
        }
#pragma unroll
        for (int p = 0; p < 2; ++p) {
            int r = p * 64 + wid * 16;
            glds16(&Bf[(bn + r + lrow) * 1024 + k0 + schunk], &Bs[bu][r * 32]);
        }
    };

    auto COMPUTE = [&](int cur) {
        half8 a[MI], b[4];
#pragma unroll
        for (int j = 0; j < 4; ++j)
            b[j] = *(const half8*)&Bs[cur][(wn + j * 16 + ln) * 32 + kswz];
#pragma unroll
        for (int i = 0; i < MI; ++i)
            a[i] = *(const half8*)&As[cur][(wm + i * 16 + ln) * 32 + kswz];
#pragma unroll
        for (int i = 0; i < MI; ++i)
#pragma unroll
            for (int j = 0; j < 4; ++j)
                acc[i][j] = MFMAH(a[i], b[j], acc[i][j]);
    };

    GSTAGE(0, 0);
    asm volatile("s_waitcnt vmcnt(0)" ::: "memory");
    __syncthreads();

    for (int k0 = 0; k0 < 1024 - 32; k0 += 32) {
        const int cur = (k0 >> 5) & 1;
        GSTAGE(k0 + 32, cur ^ 1);        // prefetch next step (in flight during compute)
        COMPUTE(cur);
        asm volatile("s_waitcnt vmcnt(0)" ::: "memory");
        __syncthreads();
    }
    COMPUTE(1);                          // step 31 (cur = 1), no prefetch

    if (VtOut && bn >= 2048) {
        // transposed store: VtOut[d][seq]; lane holds 4 consecutive seq rows.
#pragma unroll
        for (int i = 0; i < MI; ++i)
#pragma unroll
            for (int j = 0; j < 4; ++j) {
                int col = bn + wn + j * 16 + ln;
                float bv = bias[col];
                int colV = col - 2048;
                int row0 = bm + wm + i * 16 + quad * 4;
                ushort4 pk = make_ushort4(f2h(acc[i][j][0] + bv), f2h(acc[i][j][1] + bv),
                                          f2h(acc[i][j][2] + bv), f2h(acc[i][j][3] + bv));
                *(ushort4*)&VtOut[colV * 4096 + row0] = pk;
            }
        return;
    }

#pragma unroll
    for (int i = 0; i < MI; ++i)
#pragma unroll
        for (int j = 0; j < 4; ++j) {
            int col = bn + wn + j * 16 + ln;
            float bv = bias[col];
#pragma unroll
            for (int r = 0; r < 4; ++r) {
                int row = bm + wm + i * 16 + quad * 4 + r;
                float v = acc[i][j][r] + bv;
                if (Cb) Cb[row * ldc + col] = f2h(v);
                else    Cf[row * ldc + col] = v;
            }
        }
}

// ============ flash attention, fp16 MFMA, transposed S/O ============
// R5 configuration (best measured: 56.0us). Block: 4 waves x 32 q-rows =
// 128 q of one (b,h). K AND V staged via glds16 into packed [row][32]-per-
// half layout with XOR chunk swizzle both-sides -> 0 bank conflicts.
// Cross-tile pipeline: stage(kt+2) || QK(kt+1)+exp || PV(kt); even/odd
// phases, named pfA/pfB, peeled tail, branch-free body. Scores in log2
// domain -> p = v_exp_f32 raw. Row sums via ones-MFMA.
__global__ __launch_bounds__(256) void flash_f16(
    const u16* __restrict__ QKV, const u16* __restrict__ Vt,
    u16* __restrict__ AO) {
    __shared__ u16 Ks[2][2][64 * 32];   // [buf][d-half][key row][32], chunk-swizzled
    __shared__ u16 Vs[2][2][64 * 32];   // [buf][key-half][d row][32], chunk-swizzled

    const int tid = threadIdx.x;
    const int wid = tid >> 6, lane = tid & 63;
    const int ln = lane & 15, quad = lane >> 4;
    const int qt = blockIdx.x, h = blockIdx.y, b = blockIdx.z;
    const int rowbase = b * NQ;
    const int col0 = h * 64;
    const int q0 = rowbase + qt * 128 + wid * 32;
    const int lrow = lane >> 2;          // DMA: row within 16-row group
    const int kchunk = ((lane & 3) ^ ((lrow >> 1) & 3)) * 8;
    const int kswz = (quad ^ ((ln >> 1) & 3)) * 8;

    const half8 ones = {(f16)1, (f16)1, (f16)1, (f16)1,
                        (f16)1, (f16)1, (f16)1, (f16)1};

    // Q fragments (B-operand: lane ln = q-row q0+mi*16+ln, k = kc*32+quad*8+j)
    half8 qf[2][2];
#pragma unroll
    for (int mi = 0; mi < 2; ++mi)
#pragma unroll
        for (int kc = 0; kc < 2; ++kc)
            qf[mi][kc] = *(const half8*)&QKV[(q0 + mi * 16 + ln) * 3072 + col0 +
                                             kc * 32 + quad * 8];

    f32x4 accO[4][2];    // [a: d-subtile][mi], element (d=a*16+quad*4+r, q=mi*16+ln)
    f32x4 accS[2];       // row sums, col = q = ln
#pragma unroll
    for (int mi = 0; mi < 2; ++mi) {
        accS[mi] = (f32x4){0.f, 0.f, 0.f, 0.f};
#pragma unroll
        for (int a = 0; a < 4; ++a) accO[a][mi] = (f32x4){0.f, 0.f, 0.f, 0.f};
    }

    const int NT = NQ / 64;
    // DMA per-lane global bases (16 rows x 64B per glds16 call per wave)
    const u16* Kg = QKV + (rowbase + wid * 16 + lrow) * 3072 + 1024 + col0 + kchunk;
    const u16* Vg = Vt + (col0 + wid * 16 + lrow) * 4096 + rowbase + kchunk;

#define STAGEK(kt2, bu)                                        \
    {                                                          \
        const u16* kg_ = Kg + (kt2) * (64 * 3072);             \
        glds16(kg_,      &Ks[bu][0][wid * 512]);               \
        glds16(kg_ + 32, &Ks[bu][1][wid * 512]);               \
    }
#define STAGEV(kt2, bu)                                        \
    {                                                          \
        const u16* vg_ = Vg + (kt2) * 64;                      \
        glds16(vg_,      &Vs[bu][0][wid * 512]);               \
        glds16(vg_ + 32, &Vs[bu][1][wid * 512]);               \
    }

    // QK^T from Ks[kb] -> exp -> butterfly -> pf (B-operand layout) + rowsum.
    auto qk_exp = [&](int kb, half8 (&pf)[2][2]) {
        // S^T = K @ Q^T : element (key = a*16+quad*4+r, q = mi*16+ln)
        f32x4 s[4][2];
#pragma unroll
        for (int a = 0; a < 4; ++a) {
            half8 kf0 = *(const half8*)&Ks[kb][0][(a * 16 + ln) * 32 + kswz];
            half8 kf1 = *(const half8*)&Ks[kb][1][(a * 16 + ln) * 32 + kswz];
#pragma unroll
            for (int mi = 0; mi < 2; ++mi) {
                f32x4 t = (f32x4){0.f, 0.f, 0.f, 0.f};
                t = MFMAH(kf0, qf[mi][0], t);
                t = MFMAH(kf1, qf[mi][1], t);
                s[a][mi] = t;
            }
        }
        // p = 2^s, pack to fp16 pairs, register butterfly to B-operand layout:
        // pf[mi][kc] element j = P[key = kc*32 + quad*8 + j][q = mi*16+ln].
#pragma unroll
        for (int mi = 0; mi < 2; ++mi)
#pragma unroll
            for (int kc = 0; kc < 2; ++kc) {
                u32 c0 = pk_h2(fexp2(s[2 * kc][mi][0]), fexp2(s[2 * kc][mi][1]));
                u32 c1 = pk_h2(fexp2(s[2 * kc][mi][2]), fexp2(s[2 * kc][mi][3]));
                u32 c2 = pk_h2(fexp2(s[2 * kc + 1][mi][0]), fexp2(s[2 * kc + 1][mi][1]));
                u32 c3 = pk_h2(fexp2(s[2 * kc + 1][mi][2]), fexp2(s[2 * kc + 1][mi][3]));
                pl32swap(c0, c2);
                pl32swap(c1, c3);
                pl16swap(c0, c2);
                pl16swap(c1, c3);
                union { u32 u[4]; half8 h; } pu;
                pu.u[0] = c0; pu.u[1] = c1; pu.u[2] = c2; pu.u[3] = c3;
                pf[mi][kc] = pu.h;
                accS[mi] = MFMAH(ones, pf[mi][kc], accS[mi]);   // row sums
            }
    };

    // O^T += V^T @ P^T from Vs[vb] : element (d = a*16+quad*4+r, q = mi*16+ln)
    auto pv = [&](const half8 (&pf)[2][2], int vb) {
#pragma unroll
        for (int a = 0; a < 4; ++a) {
            half8 vf0 = *(const half8*)&Vs[vb][0][(a * 16 + ln) * 32 + kswz];
            half8 vf1 = *(const half8*)&Vs[vb][1][(a * 16 + ln) * 32 + kswz];
#pragma unroll
            for (int mi = 0; mi < 2; ++mi) {
                accO[a][mi] = MFMAH(vf0, pf[mi][0], accO[a][mi]);
                accO[a][mi] = MFMAH(vf1, pf[mi][1], accO[a][mi]);
            }
        }
    };

    half8 pfA[2][2], pfB[2][2];

    // prologue: tile 0 staged, pfA = P(0); K(1) staged for first phase
    STAGEK(0, 0);
    STAGEV(0, 0);
    asm volatile("s_waitcnt vmcnt(0)" ::: "memory");
    __syncthreads();
    STAGEK(1, 1);
    qk_exp(0, pfA);
    asm volatile("s_waitcnt vmcnt(0)" ::: "memory");
    __syncthreads();

    // main loop: branch-free even/odd phases, 2 tiles/iteration.
    // phase A: writes Ks[0],Vs[1]; reads Ks[1](QK kt+1), Vs[0](PV kt).
    // phase B: writes Ks[1],Vs[0]; reads Ks[0](QK kt+2), Vs[1](PV kt+1).
    for (int kt = 0; kt < NT - 2; kt += 2) {
        STAGEK(kt + 2, 0);
        STAGEV(kt + 1, 1);
        qk_exp(1, pfB);          // tile kt+1 (exp overlaps PV below)
        pv(pfA, 0);              // tile kt
        asm volatile("s_waitcnt vmcnt(0)" ::: "memory");
        __syncthreads();

        STAGEK(kt + 3, 1);
        STAGEV(kt + 2, 0);
        qk_exp(0, pfA);          // tile kt+2
        pv(pfB, 1);              // tile kt+1
        asm volatile("s_waitcnt vmcnt(0)" ::: "memory");
        __syncthreads();
    }
    // tail: tiles NT-2, NT-1 (state: pfA = P(NT-2), Ks[1]=K(NT-1), Vs[0]=V(NT-2))
    STAGEV(NT - 1, 1);
    qk_exp(1, pfB);              // tile NT-1
    pv(pfA, 0);                  // tile NT-2
    asm volatile("s_waitcnt vmcnt(0)" ::: "memory");
    __syncthreads();
    pv(pfB, 1);                  // tile NT-1
#undef STAGEK
#undef STAGEV

    // epilogue: normalize (inv uniform per lane), single fp16 AO, ushort4 stores
#pragma unroll
    for (int mi = 0; mi < 2; ++mi) {
        float inv = 1.f / accS[mi][0];
        int q = q0 + mi * 16 + ln;
#pragma unroll
        for (int a = 0; a < 4; ++a) {
            ushort4 pk = make_ushort4(f2h(accO[a][mi][0] * inv),
                                      f2h(accO[a][mi][1] * inv),
                                      f2h(accO[a][mi][2] * inv),
                                      f2h(accO[a][mi][3] * inv));
            *(ushort4*)&AO[q * 1024 + col0 + a * 16 + quad * 4] = pk;
        }
    }
}

// ============ launch ============
extern "C" void kernel_launch(void* const* d_in, const int* in_sizes, int n_in,
                              void* d_out, int out_size, void* d_ws, size_t ws_size,
                              hipStream_t stream) {
    const float* x = (const float*)d_in[0];
    const float* w[4]  = {(const float*)d_in[1],  (const float*)d_in[5],
                          (const float*)d_in[9],  (const float*)d_in[13]};
    const float* bv[4] = {(const float*)d_in[2],  (const float*)d_in[6],
                          (const float*)d_in[10], (const float*)d_in[14]};
    const float* dw[4] = {(const float*)d_in[3],  (const float*)d_in[7],
                          (const float*)d_in[11], (const float*)d_in[15]};
    const float* db[4] = {(const float*)d_in[4],  (const float*)d_in[8],
                          (const float*)d_in[12], (const float*)d_in[16]};

    u16* p = (u16*)d_ws;
    u16* Wf  = p; p += 4096 * 1024;
    u16* xf  = p; p += 4096 * 1024;
    u16* QKV = p; p += 4096 * 3072;   // V third unused (lives in Vt)
    u16* Vt  = p; p += 1024 * 4096;
    float* ball = (float*)p;          // 4096 floats
    // AO aliases xf: x is dead after the QKV GEMM completes (same stream).
    u16* AO = xf;

    // merged weights + bias pack (fused: blocks 4096..4111 do the bias)
    merge_w16<<<4112, 256, 0, stream>>>(w[0], dw[0], db[0], w[1], dw[1], db[1],
                                        w[2], dw[2], db[2], w[3], dw[3], db[3], Wf,
                                        bv[0], bv[1], bv[2], bv[3], ball);
    xcast<<<4096, 256, 0, stream>>>(x, xf);

    // fused q,k,v projection: q,k -> QKV fp16 row-major; v -> Vt transposed
    gemm_f16<128><<<dim3(24, 32), 256, 0, stream>>>(xf, Wf, ball,
                                                    nullptr, QKV, 3072, Vt);

    flash_f16<<<dim3(NQ / 128, 16, NB), 256, 0, stream>>>(QKV, Vt, AO);

    // o projection: fp32 out, TM=64 -> 512 blocks (2 blocks/CU)
    gemm_f16<64><<<dim3(8, 64), 256, 0, stream>>>(AO, Wf + 3072 * 1024,
                                                  ball + 3072, (float*)d_out, nullptr, 1024,
                                                  nullptr);
}

// Round 8
// 217.696 us; speedup vs baseline: 1.0586x; 1.0344x over previous
//
#include <hip/hip_runtime.h>
#include <hip/hip_bf16.h>

#define NQ 2048
#define NB 2

typedef unsigned short u16;
typedef unsigned int u32;
typedef _Float16 f16;
typedef __attribute__((ext_vector_type(8))) _Float16 half8;
typedef __attribute__((ext_vector_type(2))) __fp16 fp16x2;
typedef __attribute__((ext_vector_type(4))) float f32x4;
typedef __attribute__((ext_vector_type(2))) unsigned int u32x2;

#define MFMAH(A, B, C) __builtin_amdgcn_mfma_f32_16x16x32_f16(A, B, C, 0, 0, 0)

__device__ __forceinline__ u16 f2h(float x) {
    f16 h = (f16)x;                 // v_cvt_f16_f32 (RNE)
    return *(u16*)&h;
}
// packed f32x2 -> fp16x2 (v_cvt_pkrtz_f16_f32), returned as u32
__device__ __forceinline__ u32 pk_h2(float a, float b) {
    union { fp16x2 v; u32 u; } c;
    c.v = __builtin_amdgcn_cvt_pkrtz(a, b);
    return c.u;
}
// raw v_exp_f32 (2^x)
__device__ __forceinline__ float fexp2(float x) {
#if __has_builtin(__builtin_amdgcn_exp2f)
    return __builtin_amdgcn_exp2f(x);
#else
    return exp2f(x);
#endif
}
// async global->LDS DMA, 16B/lane; lds dest is wave-uniform base + lane*16
__device__ __forceinline__ void glds16(const u16* g, u16* l) {
    typedef const __attribute__((address_space(1))) u16 gu16;
    typedef __attribute__((address_space(3))) u16 lu16;
    __builtin_amdgcn_global_load_lds((gu16*)g, (lu16*)l, 16, 0, 0);
}
// counted vmcnt wait (compile-time N)
template <int N> __device__ __forceinline__ void waitvm() {
    if constexpr (N == 0) asm volatile("s_waitcnt vmcnt(0)" ::: "memory");
    else if constexpr (N == 3) asm volatile("s_waitcnt vmcnt(3)" ::: "memory");
    else if constexpr (N == 4) asm volatile("s_waitcnt vmcnt(4)" ::: "memory");
    else static_assert(N == 0 || N == 3 || N == 4, "add vmcnt case");
}
// VALU cross-lane swaps (gfx950): a/b both updated.
__device__ __forceinline__ void pl32swap(u32& a, u32& b) {
#if __has_builtin(__builtin_amdgcn_permlane32_swap)
    u32x2 r = __builtin_amdgcn_permlane32_swap(a, b, false, false);
    a = r[0]; b = r[1];
#else
    asm volatile("v_permlane32_swap_b32 %0, %1" : "+v"(a), "+v"(b));
#endif
}
__device__ __forceinline__ void pl16swap(u32& a, u32& b) {
#if __has_builtin(__builtin_amdgcn_permlane16_swap)
    u32x2 r = __builtin_amdgcn_permlane16_swap(a, b, false, false);
    a = r[0]; b = r[1];
#else
    asm volatile("v_permlane16_swap_b32 %0, %1" : "+v"(a), "+v"(b));
#endif
}

// q-scale: 1/sqrt(64) * log2(e), so attention scores land in log2 domain
#define QSCALE 0.18033688011112042f

// ============ fused prep: merged weights + x cast + bias pack ============
// blocks [0,4096): W + dB@dW -> fp16 (rows 0..3071 = q,k,v; 3072.. = o)
// blocks [4096,8192): x -> fp16
// blocks [8192,8208): bias pack
__global__ __launch_bounds__(256) void prep(
    const float* __restrict__ w0, const float* __restrict__ dw0, const float* __restrict__ db0,
    const float* __restrict__ w1, const float* __restrict__ dw1, const float* __restrict__ db1,
    const float* __restrict__ w2, const float* __restrict__ dw2, const float* __restrict__ db2,
    const float* __restrict__ w3, const float* __restrict__ dw3, const float* __restrict__ db3,
    u16* __restrict__ Wf,
    const float* __restrict__ x, u16* __restrict__ xf,
    const float* __restrict__ b0, const float* __restrict__ b1,
    const float* __restrict__ b2, const float* __restrict__ b3,
    float* __restrict__ ball) {
    const int bid = blockIdx.x;
    if (bid >= 8192) {
        int t = (bid - 8192) * 256 + threadIdx.x;   // 4096
        int which = t >> 10;
        const float* B = (which == 0) ? b0 : (which == 1) ? b1 : (which == 2) ? b2 : b3;
        float v = B[t & 1023];
        if (which == 0) v *= QSCALE;
        ball[t] = v;
        return;
    }
    if (bid >= 4096) {
        int i4 = ((bid - 4096) * 256 + threadIdx.x) * 4;
        float4 v = *(const float4*)&x[i4];
        *(uint2*)&xf[i4] = make_uint2(pk_h2(v.x, v.y), pk_h2(v.z, v.w));
        return;
    }
    int i4 = (bid * 256 + threadIdx.x) * 4;   // over 4096*1024
    int row = i4 >> 10, col = i4 & 1023;
    int which = row >> 10, lr = row & 1023;
    const float* W  = (which == 0) ? w0  : (which == 1) ? w1  : (which == 2) ? w2  : w3;
    const float* dW = (which == 0) ? dw0 : (which == 1) ? dw1 : (which == 2) ? dw2 : dw3;
    const float* dB = (which == 0) ? db0 : (which == 1) ? db1 : (which == 2) ? db2 : db3;
    float4 acc = *(const float4*)&W[lr * 1024 + col];
#pragma unroll
    for (int r = 0; r < 5; ++r) {
        float s = dB[lr * 5 + r];                    // block-uniform
        float4 w4 = *(const float4*)&dW[r * 1024 + col];
        acc.x += s * w4.x; acc.y += s * w4.y;
        acc.z += s * w4.z; acc.w += s * w4.w;
    }
    if (which == 0) { acc.x *= QSCALE; acc.y *= QSCALE; acc.z *= QSCALE; acc.w *= QSCALE; }
    ushort4 o = make_ushort4(f2h(acc.x), f2h(acc.y), f2h(acc.z), f2h(acc.w));
    *(ushort4*)&Wf[i4] = o;
}

// ============ fp16 GEMM: C[4096][N] = A @ B^T + bias ============
// TM x 128 tile, BK=32 K-steps. 3-BUFFER, 2-AHEAD pipeline with COUNTED
// vmcnt (T4): per step issue STAGE(k+2), compute buf k%3, then wait
// vmcnt(LPS) -- only step k+1's loads must land; step k+2's stay in flight
// ACROSS the barrier. (R7 lesson: 2-buf with vmcnt(0) drains the just-issued
// loads every step -> latency exposed; counted vmcnt IS the pipeline gain.)
// Packed [row][32] layout, XOR chunk swizzle both-sides -> 0 conflicts.
// If VtOut: column blocks bn >= 2048 (V third) store TRANSPOSED.
template <int TM>
__global__ __launch_bounds__(256) void gemm_f16(
    const u16* __restrict__ Af, const u16* __restrict__ Bf,
    const float* __restrict__ bias,
    float* __restrict__ Cf, u16* __restrict__ Cb, int ldc,
    u16* __restrict__ VtOut) {
    constexpr int MI = TM / 32;               // m-subtiles per wave
    constexpr int LPS = TM / 64 + 2;          // glds16 issued per wave per step
    __shared__ u16 As[3][TM * 32];            // [buf][row*32]
    __shared__ u16 Bs[3][128 * 32];
    const int tid = threadIdx.x;
    const int wid = tid >> 6, lane = tid & 63;
    const int ln = lane & 15, quad = lane >> 4;
    const int bm = blockIdx.y * TM, bn = blockIdx.x * 128;
    const int wm = (wid >> 1) * (TM / 2), wn = (wid & 1) * 64;
    const int lrow = lane >> 2;               // DMA: row within 16-row group
    // DMA source chunk (pre-swizzle): lane l fetches logical chunk (l&3)^((lrow>>1)&3)
    const int schunk = ((lane & 3) ^ ((lrow >> 1) & 3)) * 8;
    // fragment-read physical chunk: quad ^ ((ln>>1)&3)
    const int kswz = (quad ^ ((ln >> 1) & 3)) * 8;

    f32x4 acc[MI][4];
#pragma unroll
    for (int i = 0; i < MI; ++i)
#pragma unroll
        for (int j = 0; j < 4; ++j) acc[i][j] = (f32x4){0.f, 0.f, 0.f, 0.f};

    auto GSTAGE = [&](int s, int bu) {        // stage K-step s (cols s*32..)
#pragma unroll
        for (int p = 0; p < TM / 64; ++p) {
            int r = p * 64 + wid * 16;
            glds16(&Af[(bm + r + lrow) * 1024 + s * 32 + schunk], &As[bu][r * 32]);
        }
#pragma unroll
        for (int p = 0; p < 2; ++p) {
            int r = p * 64 + wid * 16;
            glds16(&Bf[(bn + r + lrow) * 1024 + s * 32 + schunk], &Bs[bu][r * 32]);
        }
    };

    auto COMPUTE = [&](int bu) {
        half8 a[MI], b[4];
#pragma unroll
        for (int j = 0; j < 4; ++j)
            b[j] = *(const half8*)&Bs[bu][(wn + j * 16 + ln) * 32 + kswz];
#pragma unroll
        for (int i = 0; i < MI; ++i)
            a[i] = *(const half8*)&As[bu][(wm + i * 16 + ln) * 32 + kswz];
#pragma unroll
        for (int i = 0; i < MI; ++i)
#pragma unroll
            for (int j = 0; j < 4; ++j)
                acc[i][j] = MFMAH(a[i], b[j], acc[i][j]);
    };

    // prologue: tiles 0,1 staged; wait only tile 0 (tile 1 in flight)
    GSTAGE(0, 0);
    GSTAGE(1, 1);
    waitvm<LPS>();
    __syncthreads();

    // 32 K-steps total; tile t lives in buf t%3. Main loop covers t=0..29.
    for (int s = 0; s < 30; s += 3) {
        GSTAGE(s + 2, 2); COMPUTE(0); waitvm<LPS>(); __syncthreads();
        GSTAGE(s + 3, 0); COMPUTE(1); waitvm<LPS>(); __syncthreads();
        GSTAGE(s + 4, 1); COMPUTE(2); waitvm<LPS>(); __syncthreads();
    }
    // tail: tiles 30 (buf0, already landed), 31 (buf1, drain)
    COMPUTE(0);
    waitvm<0>();
    __syncthreads();
    COMPUTE(1);

    if (VtOut && bn >= 2048) {
        // transposed store: VtOut[d][seq]; lane holds 4 consecutive seq rows.
#pragma unroll
        for (int i = 0; i < MI; ++i)
#pragma unroll
            for (int j = 0; j < 4; ++j) {
                int col = bn + wn + j * 16 + ln;
                float bv = bias[col];
                int colV = col - 2048;
                int row0 = bm + wm + i * 16 + quad * 4;
                ushort4 pk = make_ushort4(f2h(acc[i][j][0] + bv), f2h(acc[i][j][1] + bv),
                                          f2h(acc[i][j][2] + bv), f2h(acc[i][j][3] + bv));
                *(ushort4*)&VtOut[colV * 4096 + row0] = pk;
            }
        return;
    }

#pragma unroll
    for (int i = 0; i < MI; ++i)
#pragma unroll
        for (int j = 0; j < 4; ++j) {
            int col = bn + wn + j * 16 + ln;
            float bv = bias[col];
#pragma unroll
            for (int r = 0; r < 4; ++r) {
                int row = bm + wm + i * 16 + quad * 4 + r;
                float v = acc[i][j][r] + bv;
                if (Cb) Cb[row * ldc + col] = f2h(v);
                else    Cf[row * ldc + col] = v;
            }
        }
}

// ============ flash attention, fp16 MFMA, transposed S/O ============
// R5/R7 configuration (best measured: 56.0-56.4us, invariant across 4
// structural probes -> at its schedule's limit). Block: 4 waves x 32 q-rows.
// K AND V staged via glds16, packed [row][32]-per-half, XOR chunk swizzle
// both-sides -> 0 bank conflicts. Cross-tile pipeline:
// stage(kt+2) || QK(kt+1)+exp || PV(kt). Scores in log2 domain; row sums
// via ones-MFMA; in-register cvt_pkrtz + permlane butterfly for S->P.
__global__ __launch_bounds__(256) void flash_f16(
    const u16* __restrict__ QKV, const u16* __restrict__ Vt,
    u16* __restrict__ AO) {
    __shared__ u16 Ks[2][2][64 * 32];   // [buf][d-half][key row][32], chunk-swizzled
    __shared__ u16 Vs[2][2][64 * 32];   // [buf][key-half][d row][32], chunk-swizzled

    const int tid = threadIdx.x;
    const int wid = tid >> 6, lane = tid & 63;
    const int ln = lane & 15, quad = lane >> 4;
    const int qt = blockIdx.x, h = blockIdx.y, b = blockIdx.z;
    const int rowbase = b * NQ;
    const int col0 = h * 64;
    const int q0 = rowbase + qt * 128 + wid * 32;
    const int lrow = lane >> 2;          // DMA: row within 16-row group
    const int kchunk = ((lane & 3) ^ ((lrow >> 1) & 3)) * 8;
    const int kswz = (quad ^ ((ln >> 1) & 3)) * 8;

    const half8 ones = {(f16)1, (f16)1, (f16)1, (f16)1,
                        (f16)1, (f16)1, (f16)1, (f16)1};

    // Q fragments (B-operand: lane ln = q-row q0+mi*16+ln, k = kc*32+quad*8+j)
    half8 qf[2][2];
#pragma unroll
    for (int mi = 0; mi < 2; ++mi)
#pragma unroll
        for (int kc = 0; kc < 2; ++kc)
            qf[mi][kc] = *(const half8*)&QKV[(q0 + mi * 16 + ln) * 3072 + col0 +
                                             kc * 32 + quad * 8];

    f32x4 accO[4][2];    // [a: d-subtile][mi], element (d=a*16+quad*4+r, q=mi*16+ln)
    f32x4 accS[2];       // row sums, col = q = ln
#pragma unroll
    for (int mi = 0; mi < 2; ++mi) {
        accS[mi] = (f32x4){0.f, 0.f, 0.f, 0.f};
#pragma unroll
        for (int a = 0; a < 4; ++a) accO[a][mi] = (f32x4){0.f, 0.f, 0.f, 0.f};
    }

    const int NT = NQ / 64;
    // DMA per-lane global bases (16 rows x 64B per glds16 call per wave)
    const u16* Kg = QKV + (rowbase + wid * 16 + lrow) * 3072 + 1024 + col0 + kchunk;
    const u16* Vg = Vt + (col0 + wid * 16 + lrow) * 4096 + rowbase + kchunk;

#define STAGEK(kt2, bu)                                        \
    {                                                          \
        const u16* kg_ = Kg + (kt2) * (64 * 3072);             \
        glds16(kg_,      &Ks[bu][0][wid * 512]);               \
        glds16(kg_ + 32, &Ks[bu][1][wid * 512]);               \
    }
#define STAGEV(kt2, bu)                                        \
    {                                                          \
        const u16* vg_ = Vg + (kt2) * 64;                      \
        glds16(vg_,      &Vs[bu][0][wid * 512]);               \
        glds16(vg_ + 32, &Vs[bu][1][wid * 512]);               \
    }

    // QK^T from Ks[kb] -> exp -> butterfly -> pf (B-operand layout) + rowsum.
    auto qk_exp = [&](int kb, half8 (&pf)[2][2]) {
        // S^T = K @ Q^T : element (key = a*16+quad*4+r, q = mi*16+ln)
        f32x4 s[4][2];
#pragma unroll
        for (int a = 0; a < 4; ++a) {
            half8 kf0 = *(const half8*)&Ks[kb][0][(a * 16 + ln) * 32 + kswz];
            half8 kf1 = *(const half8*)&Ks[kb][1][(a * 16 + ln) * 32 + kswz];
#pragma unroll
            for (int mi = 0; mi < 2; ++mi) {
                f32x4 t = (f32x4){0.f, 0.f, 0.f, 0.f};
                t = MFMAH(kf0, qf[mi][0], t);
                t = MFMAH(kf1, qf[mi][1], t);
                s[a][mi] = t;
            }
        }
        // p = 2^s, pack to fp16 pairs, register butterfly to B-operand layout:
        // pf[mi][kc] element j = P[key = kc*32 + quad*8 + j][q = mi*16+ln].
#pragma unroll
        for (int mi = 0; mi < 2; ++mi)
#pragma unroll
            for (int kc = 0; kc < 2; ++kc) {
                u32 c0 = pk_h2(fexp2(s[2 * kc][mi][0]), fexp2(s[2 * kc][mi][1]));
                u32 c1 = pk_h2(fexp2(s[2 * kc][mi][2]), fexp2(s[2 * kc][mi][3]));
                u32 c2 = pk_h2(fexp2(s[2 * kc + 1][mi][0]), fexp2(s[2 * kc + 1][mi][1]));
                u32 c3 = pk_h2(fexp2(s[2 * kc + 1][mi][2]), fexp2(s[2 * kc + 1][mi][3]));
                pl32swap(c0, c2);
                pl32swap(c1, c3);
                pl16swap(c0, c2);
                pl16swap(c1, c3);
                union { u32 u[4]; half8 h; } pu;
                pu.u[0] = c0; pu.u[1] = c1; pu.u[2] = c2; pu.u[3] = c3;
                pf[mi][kc] = pu.h;
                accS[mi] = MFMAH(ones, pf[mi][kc], accS[mi]);   // row sums
            }
    };

    // O^T += V^T @ P^T from Vs[vb] : element (d = a*16+quad*4+r, q = mi*16+ln)
    auto pv = [&](const half8 (&pf)[2][2], int vb) {
#pragma unroll
        for (int a = 0; a < 4; ++a) {
            half8 vf0 = *(const half8*)&Vs[vb][0][(a * 16 + ln) * 32 + kswz];
            half8 vf1 = *(const half8*)&Vs[vb][1][(a * 16 + ln) * 32 + kswz];
#pragma unroll
            for (int mi = 0; mi < 2; ++mi) {
                accO[a][mi] = MFMAH(vf0, pf[mi][0], accO[a][mi]);
                accO[a][mi] = MFMAH(vf1, pf[mi][1], accO[a][mi]);
            }
        }
    };

    half8 pfA[2][2], pfB[2][2];

    // prologue: tile 0 staged, pfA = P(0); K(1) staged for first phase
    STAGEK(0, 0);
    STAGEV(0, 0);
    asm volatile("s_waitcnt vmcnt(0)" ::: "memory");
    __syncthreads();
    STAGEK(1, 1);
    qk_exp(0, pfA);
    asm volatile("s_waitcnt vmcnt(0)" ::: "memory");
    __syncthreads();

    // main loop: branch-free even/odd phases, 2 tiles/iteration.
    // phase A: writes Ks[0],Vs[1]; reads Ks[1](QK kt+1), Vs[0](PV kt).
    // phase B: writes Ks[1],Vs[0]; reads Ks[0](QK kt+2), Vs[1](PV kt+1).
    for (int kt = 0; kt < NT - 2; kt += 2) {
        STAGEK(kt + 2, 0);
        STAGEV(kt + 1, 1);
        qk_exp(1, pfB);          // tile kt+1 (exp overlaps PV below)
        pv(pfA, 0);              // tile kt
        asm volatile("s_waitcnt vmcnt(0)" ::: "memory");
        __syncthreads();

        STAGEK(kt + 3, 1);
        STAGEV(kt + 2, 0);
        qk_exp(0, pfA);          // tile kt+2
        pv(pfB, 1);              // tile kt+1
        asm volatile("s_waitcnt vmcnt(0)" ::: "memory");
        __syncthreads();
    }
    // tail: tiles NT-2, NT-1 (state: pfA = P(NT-2), Ks[1]=K(NT-1), Vs[0]=V(NT-2))
    STAGEV(NT - 1, 1);
    qk_exp(1, pfB);              // tile NT-1
    pv(pfA, 0);                  // tile NT-2
    asm volatile("s_waitcnt vmcnt(0)" ::: "memory");
    __syncthreads();
    pv(pfB, 1);                  // tile NT-1
#undef STAGEK
#undef STAGEV

    // epilogue: normalize (inv uniform per lane), single fp16 AO, ushort4 stores
#pragma unroll
    for (int mi = 0; mi < 2; ++mi) {
        float inv = 1.f / accS[mi][0];
        int q = q0 + mi * 16 + ln;
#pragma unroll
        for (int a = 0; a < 4; ++a) {
            ushort4 pk = make_ushort4(f2h(accO[a][mi][0] * inv),
                                      f2h(accO[a][mi][1] * inv),
                                      f2h(accO[a][mi][2] * inv),
                                      f2h(accO[a][mi][3] * inv));
            *(ushort4*)&AO[q * 1024 + col0 + a * 16 + quad * 4] = pk;
        }
    }
}

// ============ launch ============
extern "C" void kernel_launch(void* const* d_in, const int* in_sizes, int n_in,
                              void* d_out, int out_size, void* d_ws, size_t ws_size,
                              hipStream_t stream) {
    const float* x = (const float*)d_in[0];
    const float* w[4]  = {(const float*)d_in[1],  (const float*)d_in[5],
                          (const float*)d_in[9],  (const float*)d_in[13]};
    const float* bv[4] = {(const float*)d_in[2],  (const float*)d_in[6],
                          (const float*)d_in[10], (const float*)d_in[14]};
    const float* dw[4] = {(const float*)d_in[3],  (const float*)d_in[7],
                          (const float*)d_in[11], (const float*)d_in[15]};
    const float* db[4] = {(const float*)d_in[4],  (const float*)d_in[8],
                          (const float*)d_in[12], (const float*)d_in[16]};

    u16* p = (u16*)d_ws;
    u16* Wf  = p; p += 4096 * 1024;
    u16* xf  = p; p += 4096 * 1024;
    u16* QKV = p; p += 4096 * 3072;   // V third unused (lives in Vt)
    u16* Vt  = p; p += 1024 * 4096;
    float* ball = (float*)p;          // 4096 floats
    // AO aliases xf: x is dead after the QKV GEMM completes (same stream).
    u16* AO = xf;

    // fused prep: merged weights + x cast + bias pack
    prep<<<8208, 256, 0, stream>>>(w[0], dw[0], db[0], w[1], dw[1], db[1],
                                   w[2], dw[2], db[2], w[3], dw[3], db[3], Wf,
                                   x, xf,
                                   bv[0], bv[1], bv[2], bv[3], ball);

    // fused q,k,v projection: q,k -> QKV fp16 row-major; v -> Vt transposed
    gemm_f16<128><<<dim3(24, 32), 256, 0, stream>>>(xf, Wf, ball,
                                                    nullptr, QKV, 3072, Vt);

    flash_f16<<<dim3(NQ / 128, 16, NB), 256, 0, stream>>>(QKV, Vt, AO);

    // o projection: fp32 out, TM=64 -> 512 blocks (2 blocks/CU)
    gemm_f16<64><<<dim3(8, 64), 256, 0, stream>>>(AO, Wf + 3072 * 1024,
                                                  ball + 3072, (float*)d_out, nullptr, 1024,
                                                  nullptr);
}

// Round 9
// 212.560 us; speedup vs baseline: 1.0841x; 1.0242x over previous
//
#include <hip/hip_runtime.h>
#include <hip/hip_bf16.h>

#define NQ 2048
#define NB 2

typedef unsigned short u16;
typedef unsigned int u32;
typedef _Float16 f16;
typedef __attribute__((ext_vector_type(8))) _Float16 half8;
typedef __attribute__((ext_vector_type(2))) __fp16 fp16x2;
typedef __attribute__((ext_vector_type(4))) float f32x4;
typedef __attribute__((ext_vector_type(2))) unsigned int u32x2;

#define MFMAH(A, B, C) __builtin_amdgcn_mfma_f32_16x16x32_f16(A, B, C, 0, 0, 0)

__device__ __forceinline__ u16 f2h(float x) {
    f16 h = (f16)x;                 // v_cvt_f16_f32 (RNE)
    return *(u16*)&h;
}
// packed f32x2 -> fp16x2 (v_cvt_pkrtz_f16_f32), returned as u32
__device__ __forceinline__ u32 pk_h2(float a, float b) {
    union { fp16x2 v; u32 u; } c;
    c.v = __builtin_amdgcn_cvt_pkrtz(a, b);
    return c.u;
}
// raw v_exp_f32 (2^x)
__device__ __forceinline__ float fexp2(float x) {
#if __has_builtin(__builtin_amdgcn_exp2f)
    return __builtin_amdgcn_exp2f(x);
#else
    return exp2f(x);
#endif
}
// async global->LDS DMA, 16B/lane; lds dest is wave-uniform base + lane*16
__device__ __forceinline__ void glds16(const u16* g, u16* l) {
    typedef const __attribute__((address_space(1))) u16 gu16;
    typedef __attribute__((address_space(3))) u16 lu16;
    __builtin_amdgcn_global_load_lds((gu16*)g, (lu16*)l, 16, 0, 0);
}
// counted vmcnt wait (compile-time N)
template <int N> __device__ __forceinline__ void waitvm() {
    if constexpr (N == 0) asm volatile("s_waitcnt vmcnt(0)" ::: "memory");
    else if constexpr (N == 3) asm volatile("s_waitcnt vmcnt(3)" ::: "memory");
    else if constexpr (N == 4) asm volatile("s_waitcnt vmcnt(4)" ::: "memory");
    else static_assert(N == 0 || N == 3 || N == 4, "add vmcnt case");
}
// VALU cross-lane swaps (gfx950): a/b both updated.
__device__ __forceinline__ void pl32swap(u32& a, u32& b) {
#if __has_builtin(__builtin_amdgcn_permlane32_swap)
    u32x2 r = __builtin_amdgcn_permlane32_swap(a, b, false, false);
    a = r[0]; b = r[1];
#else
    asm volatile("v_permlane32_swap_b32 %0, %1" : "+v"(a), "+v"(b));
#endif
}
__device__ __forceinline__ void pl16swap(u32& a, u32& b) {
#if __has_builtin(__builtin_amdgcn_permlane16_swap)
    u32x2 r = __builtin_amdgcn_permlane16_swap(a, b, false, false);
    a = r[0]; b = r[1];
#else
    asm volatile("v_permlane16_swap_b32 %0, %1" : "+v"(a), "+v"(b));
#endif
}

// q-scale: 1/sqrt(64) * log2(e), so attention scores land in log2 domain
#define QSCALE 0.18033688011112042f

// ============ fused prep: merged weights + x cast + bias pack ============
// blocks [0,4096): W + dB@dW -> fp16 (rows 0..3071 = q,k,v; 3072.. = o)
// blocks [4096,8192): x -> fp16
// blocks [8192,8208): bias pack
__global__ __launch_bounds__(256) void prep(
    const float* __restrict__ w0, const float* __restrict__ dw0, const float* __restrict__ db0,
    const float* __restrict__ w1, const float* __restrict__ dw1, const float* __restrict__ db1,
    const float* __restrict__ w2, const float* __restrict__ dw2, const float* __restrict__ db2,
    const float* __restrict__ w3, const float* __restrict__ dw3, const float* __restrict__ db3,
    u16* __restrict__ Wf,
    const float* __restrict__ x, u16* __restrict__ xf,
    const float* __restrict__ b0, const float* __restrict__ b1,
    const float* __restrict__ b2, const float* __restrict__ b3,
    float* __restrict__ ball) {
    const int bid = blockIdx.x;
    if (bid >= 8192) {
        int t = (bid - 8192) * 256 + threadIdx.x;   // 4096
        int which = t >> 10;
        const float* B = (which == 0) ? b0 : (which == 1) ? b1 : (which == 2) ? b2 : b3;
        float v = B[t & 1023];
        if (which == 0) v *= QSCALE;
        ball[t] = v;
        return;
    }
    if (bid >= 4096) {
        int i4 = ((bid - 4096) * 256 + threadIdx.x) * 4;
        float4 v = *(const float4*)&x[i4];
        *(uint2*)&xf[i4] = make_uint2(pk_h2(v.x, v.y), pk_h2(v.z, v.w));
        return;
    }
    int i4 = (bid * 256 + threadIdx.x) * 4;   // over 4096*1024
    int row = i4 >> 10, col = i4 & 1023;
    int which = row >> 10, lr = row & 1023;
    const float* W  = (which == 0) ? w0  : (which == 1) ? w1  : (which == 2) ? w2  : w3;
    const float* dW = (which == 0) ? dw0 : (which == 1) ? dw1 : (which == 2) ? dw2 : dw3;
    const float* dB = (which == 0) ? db0 : (which == 1) ? db1 : (which == 2) ? db2 : db3;
    float4 acc = *(const float4*)&W[lr * 1024 + col];
#pragma unroll
    for (int r = 0; r < 5; ++r) {
        float s = dB[lr * 5 + r];                    // block-uniform
        float4 w4 = *(const float4*)&dW[r * 1024 + col];
        acc.x += s * w4.x; acc.y += s * w4.y;
        acc.z += s * w4.z; acc.w += s * w4.w;
    }
    if (which == 0) { acc.x *= QSCALE; acc.y *= QSCALE; acc.z *= QSCALE; acc.w *= QSCALE; }
    ushort4 o = make_ushort4(f2h(acc.x), f2h(acc.y), f2h(acc.z), f2h(acc.w));
    *(ushort4*)&Wf[i4] = o;
}

// ============ fp16 GEMM: C[4096][N] = A @ B^T + bias ============
// TM x 128 tile, BK=32 K-steps. 3-BUFFER, 2-AHEAD pipeline with COUNTED
// vmcnt (T4, proven +7.5us in R8): per step issue STAGE(k+2), compute buf
// k%3, wait vmcnt(LPS) -- step k+2's loads stay in flight ACROSS the
// barrier. Packed [row][32] layout, XOR chunk swizzle both-sides.
// If VtOut: column blocks bn >= 2048 (V third) store TRANSPOSED.
template <int TM>
__global__ __launch_bounds__(256) void gemm_f16(
    const u16* __restrict__ Af, const u16* __restrict__ Bf,
    const float* __restrict__ bias,
    float* __restrict__ Cf, u16* __restrict__ Cb, int ldc,
    u16* __restrict__ VtOut) {
    constexpr int MI = TM / 32;               // m-subtiles per wave
    constexpr int LPS = TM / 64 + 2;          // glds16 issued per wave per step
    __shared__ u16 As[3][TM * 32];            // [buf][row*32]
    __shared__ u16 Bs[3][128 * 32];
    const int tid = threadIdx.x;
    const int wid = tid >> 6, lane = tid & 63;
    const int ln = lane & 15, quad = lane >> 4;
    const int bm = blockIdx.y * TM, bn = blockIdx.x * 128;
    const int wm = (wid >> 1) * (TM / 2), wn = (wid & 1) * 64;
    const int lrow = lane >> 2;               // DMA: row within 16-row group
    const int schunk = ((lane & 3) ^ ((lrow >> 1) & 3)) * 8;
    const int kswz = (quad ^ ((ln >> 1) & 3)) * 8;

    f32x4 acc[MI][4];
#pragma unroll
    for (int i = 0; i < MI; ++i)
#pragma unroll
        for (int j = 0; j < 4; ++j) acc[i][j] = (f32x4){0.f, 0.f, 0.f, 0.f};

    auto GSTAGE = [&](int s, int bu) {        // stage K-step s (cols s*32..)
#pragma unroll
        for (int p = 0; p < TM / 64; ++p) {
            int r = p * 64 + wid * 16;
            glds16(&Af[(bm + r + lrow) * 1024 + s * 32 + schunk], &As[bu][r * 32]);
        }
#pragma unroll
        for (int p = 0; p < 2; ++p) {
            int r = p * 64 + wid * 16;
            glds16(&Bf[(bn + r + lrow) * 1024 + s * 32 + schunk], &Bs[bu][r * 32]);
        }
    };

    auto COMPUTE = [&](int bu) {
        half8 a[MI], b[4];
#pragma unroll
        for (int j = 0; j < 4; ++j)
            b[j] = *(const half8*)&Bs[bu][(wn + j * 16 + ln) * 32 + kswz];
#pragma unroll
        for (int i = 0; i < MI; ++i)
            a[i] = *(const half8*)&As[bu][(wm + i * 16 + ln) * 32 + kswz];
#pragma unroll
        for (int i = 0; i < MI; ++i)
#pragma unroll
            for (int j = 0; j < 4; ++j)
                acc[i][j] = MFMAH(a[i], b[j], acc[i][j]);
    };

    // prologue: tiles 0,1 staged; wait only tile 0 (tile 1 in flight)
    GSTAGE(0, 0);
    GSTAGE(1, 1);
    waitvm<LPS>();
    __syncthreads();

    // 32 K-steps total; tile t lives in buf t%3. Main loop covers t=0..29.
    for (int s = 0; s < 30; s += 3) {
        GSTAGE(s + 2, 2); COMPUTE(0); waitvm<LPS>(); __syncthreads();
        GSTAGE(s + 3, 0); COMPUTE(1); waitvm<LPS>(); __syncthreads();
        GSTAGE(s + 4, 1); COMPUTE(2); waitvm<LPS>(); __syncthreads();
    }
    // tail: tiles 30 (buf0, already landed), 31 (buf1, drain)
    COMPUTE(0);
    waitvm<0>();
    __syncthreads();
    COMPUTE(1);

    if (VtOut && bn >= 2048) {
        // transposed store: VtOut[d][seq]; lane holds 4 consecutive seq rows.
#pragma unroll
        for (int i = 0; i < MI; ++i)
#pragma unroll
            for (int j = 0; j < 4; ++j) {
                int col = bn + wn + j * 16 + ln;
                float bv = bias[col];
                int colV = col - 2048;
                int row0 = bm + wm + i * 16 + quad * 4;
                ushort4 pk = make_ushort4(f2h(acc[i][j][0] + bv), f2h(acc[i][j][1] + bv),
                                          f2h(acc[i][j][2] + bv), f2h(acc[i][j][3] + bv));
                *(ushort4*)&VtOut[colV * 4096 + row0] = pk;
            }
        return;
    }

#pragma unroll
    for (int i = 0; i < MI; ++i)
#pragma unroll
        for (int j = 0; j < 4; ++j) {
            int col = bn + wn + j * 16 + ln;
            float bv = bias[col];
#pragma unroll
            for (int r = 0; r < 4; ++r) {
                int row = bm + wm + i * 16 + quad * 4 + r;
                float v = acc[i][j][r] + bv;
                if (Cb) Cb[row * ldc + col] = f2h(v);
                else    Cf[row * ldc + col] = v;
            }
        }
}

// ============ flash attention, fp16 MFMA, transposed S/O ============
// Block: 4 waves x 32 q-rows = 128 q of one (b,h). KVBLK=128 (this round):
// 16 key-tiles instead of 32 -> HALF the vmcnt(0)+barrier drains, which the
// R1-R8 invariance (56-57us across 4 structural probes, all pipes <40%)
// identified as the residual. Same verified schedule otherwise: glds16
// staging, packed [row][32] chunk-swizzled LDS (0 conflicts), cross-tile
// pipeline stage(kt+2) || QK(kt+1)+exp || PV(kt), in-register cvt_pkrtz +
// permlane butterfly, ones-MFMA row sums, log2-domain scores. T5 setprio
// around MFMA clusters (2 independent blocks/CU -> arbitration exists).
__global__ __launch_bounds__(256) void flash_f16(
    const u16* __restrict__ QKV, const u16* __restrict__ Vt,
    u16* __restrict__ AO) {
    __shared__ u16 Ks[2][2][128 * 32];  // [buf][d-half][key row][32], chunk-swizzled
    __shared__ u16 Vs[2][4][64 * 32];   // [buf][key-chunk][d row][32], chunk-swizzled

    const int tid = threadIdx.x;
    const int wid = tid >> 6, lane = tid & 63;
    const int ln = lane & 15, quad = lane >> 4;
    const int qt = blockIdx.x, h = blockIdx.y, b = blockIdx.z;
    const int rowbase = b * NQ;
    const int col0 = h * 64;
    const int q0 = rowbase + qt * 128 + wid * 32;
    const int lrow = lane >> 2;          // DMA: row within 16-row group
    const int kchunk = ((lane & 3) ^ ((lrow >> 1) & 3)) * 8;
    const int kswz = (quad ^ ((ln >> 1) & 3)) * 8;

    const half8 ones = {(f16)1, (f16)1, (f16)1, (f16)1,
                        (f16)1, (f16)1, (f16)1, (f16)1};

    // Q fragments (B-operand: lane ln = q-row q0+mi*16+ln, k = kc*32+quad*8+j)
    half8 qf[2][2];
#pragma unroll
    for (int mi = 0; mi < 2; ++mi)
#pragma unroll
        for (int kc = 0; kc < 2; ++kc)
            qf[mi][kc] = *(const half8*)&QKV[(q0 + mi * 16 + ln) * 3072 + col0 +
                                             kc * 32 + quad * 8];

    f32x4 accO[4][2];    // [a: d-subtile][mi], element (d=a*16+quad*4+r, q=mi*16+ln)
    f32x4 accS[2];       // row sums, col = q = ln
#pragma unroll
    for (int mi = 0; mi < 2; ++mi) {
        accS[mi] = (f32x4){0.f, 0.f, 0.f, 0.f};
#pragma unroll
        for (int a = 0; a < 4; ++a) accO[a][mi] = (f32x4){0.f, 0.f, 0.f, 0.f};
    }

    const int NT = NQ / 128;   // 16 key-tiles of 128
    // K DMA: wave wid stages key-rows wid*32 + {0..15,16..31} (2 groups x 2 halves)
    const u16* Kg = QKV + (rowbase + wid * 32 + lrow) * 3072 + 1024 + col0 + kchunk;
    // V DMA: wave wid stages d-rows wid*16+lrow, all 4 key-chunks of 32
    const u16* Vg = Vt + (col0 + wid * 16 + lrow) * 4096 + rowbase + kchunk;

#define STAGEK(kt2, bu)                                              \
    {                                                                \
        const u16* kg_ = Kg + (kt2) * (128 * 3072);                  \
        glds16(kg_,              &Ks[bu][0][wid * 1024]);            \
        glds16(kg_ + 32,         &Ks[bu][1][wid * 1024]);            \
        glds16(kg_ + 16 * 3072,      &Ks[bu][0][wid * 1024 + 512]);  \
        glds16(kg_ + 16 * 3072 + 32, &Ks[bu][1][wid * 1024 + 512]);  \
    }
#define STAGEV(kt2, bu)                                        \
    {                                                          \
        const u16* vg_ = Vg + (kt2) * 128;                     \
        glds16(vg_,      &Vs[bu][0][wid * 512]);               \
        glds16(vg_ + 32, &Vs[bu][1][wid * 512]);               \
        glds16(vg_ + 64, &Vs[bu][2][wid * 512]);               \
        glds16(vg_ + 96, &Vs[bu][3][wid * 512]);               \
    }

    // QK^T half (keys ah*64..ah*64+63) from Ks[kb] -> exp -> butterfly ->
    // pf[mi][ah*2], pf[mi][ah*2+1] (B-operand layout) + rowsum.
    auto qk_half = [&](int kb, int ah, half8 (&pf)[2][4]) {
        f32x4 s[4][2];
        __builtin_amdgcn_s_setprio(1);
#pragma unroll
        for (int a4 = 0; a4 < 4; ++a4) {
            int a = ah * 4 + a4;
            half8 kf0 = *(const half8*)&Ks[kb][0][(a * 16 + ln) * 32 + kswz];
            half8 kf1 = *(const half8*)&Ks[kb][1][(a * 16 + ln) * 32 + kswz];
#pragma unroll
            for (int mi = 0; mi < 2; ++mi) {
                f32x4 t = (f32x4){0.f, 0.f, 0.f, 0.f};
                t = MFMAH(kf0, qf[mi][0], t);
                t = MFMAH(kf1, qf[mi][1], t);
                s[a4][mi] = t;
            }
        }
        __builtin_amdgcn_s_setprio(0);
        // p = 2^s, pack, butterfly: pf[mi][kc] elem j = P[key=kc*32+quad*8+j]
#pragma unroll
        for (int mi = 0; mi < 2; ++mi)
#pragma unroll
            for (int kc2 = 0; kc2 < 2; ++kc2) {
                u32 c0 = pk_h2(fexp2(s[2 * kc2][mi][0]), fexp2(s[2 * kc2][mi][1]));
                u32 c1 = pk_h2(fexp2(s[2 * kc2][mi][2]), fexp2(s[2 * kc2][mi][3]));
                u32 c2 = pk_h2(fexp2(s[2 * kc2 + 1][mi][0]), fexp2(s[2 * kc2 + 1][mi][1]));
                u32 c3 = pk_h2(fexp2(s[2 * kc2 + 1][mi][2]), fexp2(s[2 * kc2 + 1][mi][3]));
                pl32swap(c0, c2);
                pl32swap(c1, c3);
                pl16swap(c0, c2);
                pl16swap(c1, c3);
                union { u32 u[4]; half8 h; } pu;
                pu.u[0] = c0; pu.u[1] = c1; pu.u[2] = c2; pu.u[3] = c3;
                pf[mi][ah * 2 + kc2] = pu.h;
                accS[mi] = MFMAH(ones, pf[mi][ah * 2 + kc2], accS[mi]);   // row sums
            }
    };

    // O^T += V^T @ P^T over 128 keys (4 chunks) from Vs[vb]
    auto pv = [&](const half8 (&pf)[2][4], int vb) {
        __builtin_amdgcn_s_setprio(1);
#pragma unroll
        for (int a = 0; a < 4; ++a) {
            half8 vf0 = *(const half8*)&Vs[vb][0][(a * 16 + ln) * 32 + kswz];
            half8 vf1 = *(const half8*)&Vs[vb][1][(a * 16 + ln) * 32 + kswz];
            half8 vf2 = *(const half8*)&Vs[vb][2][(a * 16 + ln) * 32 + kswz];
            half8 vf3 = *(const half8*)&Vs[vb][3][(a * 16 + ln) * 32 + kswz];
#pragma unroll
            for (int mi = 0; mi < 2; ++mi) {
                accO[a][mi] = MFMAH(vf0, pf[mi][0], accO[a][mi]);
                accO[a][mi] = MFMAH(vf1, pf[mi][1], accO[a][mi]);
                accO[a][mi] = MFMAH(vf2, pf[mi][2], accO[a][mi]);
                accO[a][mi] = MFMAH(vf3, pf[mi][3], accO[a][mi]);
            }
        }
        __builtin_amdgcn_s_setprio(0);
    };

    half8 pfA[2][4], pfB[2][4];

    // prologue: tile 0 staged, pfA = P(0); K(1) staged for first phase
    STAGEK(0, 0);
    STAGEV(0, 0);
    asm volatile("s_waitcnt vmcnt(0)" ::: "memory");
    __syncthreads();
    STAGEK(1, 1);
    qk_half(0, 0, pfA);
    qk_half(0, 1, pfA);
    asm volatile("s_waitcnt vmcnt(0)" ::: "memory");
    __syncthreads();

    // main loop: branch-free even/odd phases, 2 tiles/iteration.
    // phase A: writes Ks[0],Vs[1]; reads Ks[1](QK kt+1), Vs[0](PV kt).
    // phase B: writes Ks[1],Vs[0]; reads Ks[0](QK kt+2), Vs[1](PV kt+1).
    for (int kt = 0; kt < NT - 2; kt += 2) {
        STAGEK(kt + 2, 0);
        STAGEV(kt + 1, 1);
        qk_half(1, 0, pfB);      // tile kt+1 (exp overlaps PV below)
        qk_half(1, 1, pfB);
        pv(pfA, 0);              // tile kt
        asm volatile("s_waitcnt vmcnt(0)" ::: "memory");
        __syncthreads();

        STAGEK(kt + 3, 1);
        STAGEV(kt + 2, 0);
        qk_half(0, 0, pfA);      // tile kt+2
        qk_half(0, 1, pfA);
        pv(pfB, 1);              // tile kt+1
        asm volatile("s_waitcnt vmcnt(0)" ::: "memory");
        __syncthreads();
    }
    // tail: tiles NT-2, NT-1 (state: pfA = P(NT-2), Ks[1]=K(NT-1), Vs[0]=V(NT-2))
    STAGEV(NT - 1, 1);
    qk_half(1, 0, pfB);          // tile NT-1
    qk_half(1, 1, pfB);
    pv(pfA, 0);                  // tile NT-2
    asm volatile("s_waitcnt vmcnt(0)" ::: "memory");
    __syncthreads();
    pv(pfB, 1);                  // tile NT-1
#undef STAGEK
#undef STAGEV

    // epilogue: normalize (inv uniform per lane), single fp16 AO, ushort4 stores
#pragma unroll
    for (int mi = 0; mi < 2; ++mi) {
        float inv = 1.f / accS[mi][0];
        int q = q0 + mi * 16 + ln;
#pragma unroll
        for (int a = 0; a < 4; ++a) {
            ushort4 pk = make_ushort4(f2h(accO[a][mi][0] * inv),
                                      f2h(accO[a][mi][1] * inv),
                                      f2h(accO[a][mi][2] * inv),
                                      f2h(accO[a][mi][3] * inv));
            *(ushort4*)&AO[q * 1024 + col0 + a * 16 + quad * 4] = pk;
        }
    }
}

// ============ launch ============
extern "C" void kernel_launch(void* const* d_in, const int* in_sizes, int n_in,
                              void* d_out, int out_size, void* d_ws, size_t ws_size,
                              hipStream_t stream) {
    const float* x = (const float*)d_in[0];
    const float* w[4]  = {(const float*)d_in[1],  (const float*)d_in[5],
                          (const float*)d_in[9],  (const float*)d_in[13]};
    const float* bv[4] = {(const float*)d_in[2],  (const float*)d_in[6],
                          (const float*)d_in[10], (const float*)d_in[14]};
    const float* dw[4] = {(const float*)d_in[3],  (const float*)d_in[7],
                          (const float*)d_in[11], (const float*)d_in[15]};
    const float* db[4] = {(const float*)d_in[4],  (const float*)d_in[8],
                          (const float*)d_in[12], (const float*)d_in[16]};

    u16* p = (u16*)d_ws;
    u16* Wf  = p; p += 4096 * 1024;
    u16* xf  = p; p += 4096 * 1024;
    u16* QKV = p; p += 4096 * 3072;   // V third unused (lives in Vt)
    u16* Vt  = p; p += 1024 * 4096;
    float* ball = (float*)p;          // 4096 floats
    // AO aliases xf: x is dead after the QKV GEMM completes (same stream).
    u16* AO = xf;

    // fused prep: merged weights + x cast + bias pack
    prep<<<8208, 256, 0, stream>>>(w[0], dw[0], db[0], w[1], dw[1], db[1],
                                   w[2], dw[2], db[2], w[3], dw[3], db[3], Wf,
                                   x, xf,
                                   bv[0], bv[1], bv[2], bv[3], ball);

    // fused q,k,v projection: q,k -> QKV fp16 row-major; v -> Vt transposed
    gemm_f16<128><<<dim3(24, 32), 256, 0, stream>>>(xf, Wf, ball,
                                                    nullptr, QKV, 3072, Vt);

    flash_f16<<<dim3(NQ / 128, 16, NB), 256, 0, stream>>>(QKV, Vt, AO);

    // o projection: fp32 out, TM=64 -> 512 blocks (2 blocks/CU)
    gemm_f16<64><<<dim3(8, 64), 256, 0, stream>>>(AO, Wf + 3072 * 1024,
                                                  ball + 3072, (float*)d_out, nullptr, 1024,
                                                  nullptr);
}